// Round 8
// baseline (29.477 us; speedup 1.0000x reference)
//
#include <hip/hip_runtime.h>
#include <hip/hip_fp16.h>

#define HOURS 24
#define RPB 256          // rows per tile (= blockDim)
#define PSTR 25          // dwords per row in LDS: 24 half2 + 1 pad (gcd(25,32)=1)
#define GRID_MAIN 640    // 640 blocks x 3 tiles = 1920 tiles; <=3 blocks/CU resident

// Workspace: float partials[6][nblocks]
// 0 sum(yp-yt)^2 all | 1 sum(yp-yt)^2 daytime | 2 sum(p_pv-t_pv)^2
// 3 sum(p_pt-t_pt)^2 | 4 sum mse_win (valid)  | 5 count valid

__device__ __forceinline__ void stage_tile(__half2* __restrict__ buf, int tid,
                                           const float4* __restrict__ a,
                                           const float4* __restrict__ b,
                                           float& s_sq, float& s_day) {
#pragma unroll
  for (int j = 0; j < 6; ++j) {
    int f4 = tid + j * 256;              // lane-contiguous float4 index within tile
    int pa0 = f4 * 4 + f4 / 6;           // padded addr: d + d/24, d = 4*f4 (24%4==0)
    buf[pa0 + 0] = __floats2half2_rn(a[j].x, b[j].x);
    buf[pa0 + 1] = __floats2half2_rn(a[j].y, b[j].y);
    buf[pa0 + 2] = __floats2half2_rn(a[j].z, b[j].z);
    buf[pa0 + 3] = __floats2half2_rn(a[j].w, b[j].w);
    // fused fp32 elementwise MSE (exact inputs)
    int h0 = 4 * (f4 % 6);               // hour of .x in {0,4,8,12,16,20}
    float dx = b[j].x - a[j].x, dy = b[j].y - a[j].y;
    float dz = b[j].z - a[j].z, dw = b[j].w - a[j].w;
    float qx = dx * dx, qy = dy * dy, qz = dz * dz, qw = dw * dw;
    s_sq += qx + qy + qz + qw;
    s_day += ((h0 + 0 >= 6) & (h0 + 0 <= 20)) ? qx : 0.f;
    s_day += ((h0 + 1 >= 6) & (h0 + 1 <= 20)) ? qy : 0.f;
    s_day += ((h0 + 2 >= 6) & (h0 + 2 <= 20)) ? qz : 0.f;
    s_day += ((h0 + 3 >= 6) & (h0 + 3 <= 20)) ? qw : 0.f;
  }
}

__device__ __forceinline__ void compute_row(const __half2* __restrict__ row,
                                            float& s_pv, float& s_pt,
                                            float& s_shape, float& s_valid) {
  // pass A: daytime max/argmax (first-max semantics)
  float mt = -1e30f, mp = -1e30f;
  int idx = 6;
#pragma unroll
  for (int h = 6; h <= 20; ++h) {
    __half2 v = row[h];
    float th = __low2float(v), ph = __high2float(v);
    if (th > mt) { mt = th; idx = h; }
    mp = fmaxf(mp, ph);
  }
  // pass B: softmax sums (T=0.1) + windowed maxima & moment sums
  int ws = idx - 2;                      // [4,18]; window [ws,ws+5) within [4,23)
  float den_t = 0.f, nv_t = 0.f, nt_t = 0.f;
  float den_p = 0.f, nv_p = 0.f, nt_p = 0.f;
  float tmax = -1e30f, pmax = -1e30f;
  float St2 = 0.f, Sp2 = 0.f, Stp = 0.f;
#pragma unroll
  for (int h = 4; h <= 22; ++h) {
    __half2 v = row[h];
    float th = __low2float(v), ph = __high2float(v);
    if (h >= 6 && h <= 20) {
      float et = __expf((th - mt) * 10.f);
      den_t += et; nv_t += et * th; nt_t += et * (float)h;
      float ep = __expf((ph - mp) * 10.f);
      den_p += ep; nv_p += ep * ph; nt_p += ep * (float)h;
    }
    bool in = (h >= ws) & (h < ws + 5);
    if (in) {
      tmax = fmaxf(tmax, th); pmax = fmaxf(pmax, ph);
      St2 += th * th; Sp2 += ph * ph; Stp += th * ph;
    }
  }
  float r_t = __builtin_amdgcn_rcpf(den_t);
  float r_p = __builtin_amdgcn_rcpf(den_p);
  float dv  = nv_p * r_p - nv_t * r_t;
  float dtm = nt_p * r_p - nt_t * r_t;
  s_pv += dv * dv;
  s_pt += dtm * dtm;
  // sum_W (p*rp - t*rt)^2 = rp^2*Sp2 + rt^2*St2 - 2*rp*rt*Stp
  bool valid = tmax > 1e-6f;
  float tms = valid ? tmax : 1.0f;
  float rt = __builtin_amdgcn_rcpf(tms);
  float rp = __builtin_amdgcn_rcpf(pmax + 1e-6f);
  float aa = rp * rp * Sp2 + rt * rt * St2 - 2.f * rp * rt * Stp;
  if (valid) { s_shape += aa * 0.2f; s_valid += 1.0f; }
}

__global__ __launch_bounds__(256, 3) void peakloss_main(
    const float* __restrict__ ypred, const float* __restrict__ ytrue,
    float* __restrict__ partials, int nrows, int nblocks) {
  __shared__ __half2 ltp[2][RPB * PSTR];   // 2 x 25.6 KB double buffer
  const int tid = threadIdx.x;
  const int G = gridDim.x;
  const int ntf = nrows / RPB;             // full tiles
  const int rem = nrows - ntf * RPB;

  float s_sq = 0.f, s_day = 0.f, s_pv = 0.f, s_pt = 0.f, s_shape = 0.f, s_valid = 0.f;
  float4 a[6], b[6];

  int tile = blockIdx.x;
  if (tile < ntf) {
    // prologue: load + stage tile -> buf0
    {
      const float4* t4 = (const float4*)(ytrue + (size_t)tile * RPB * HOURS);
      const float4* p4 = (const float4*)(ypred + (size_t)tile * RPB * HOURS);
#pragma unroll
      for (int j = 0; j < 6; ++j) { a[j] = t4[tid + j * 256]; b[j] = p4[tid + j * 256]; }
      stage_tile(ltp[0], tid, a, b, s_sq, s_day);
      __syncthreads();
    }
    int cur = 0;
    for (;;) {
      int nxt = tile + G;
      bool has = nxt < ntf;
      if (has) {                           // issue next tile's loads EARLY
        const float4* t4 = (const float4*)(ytrue + (size_t)nxt * RPB * HOURS);
        const float4* p4 = (const float4*)(ypred + (size_t)nxt * RPB * HOURS);
#pragma unroll
        for (int j = 0; j < 6; ++j) { a[j] = t4[tid + j * 256]; b[j] = p4[tid + j * 256]; }
      }
      compute_row(&ltp[cur][tid * PSTR], s_pv, s_pt, s_shape, s_valid);  // hides HBM
      if (!has) break;
      stage_tile(ltp[cur ^ 1], tid, a, b, s_sq, s_day);  // write LATE (after compute)
      __syncthreads();
      cur ^= 1;
      tile = nxt;
    }
  }

  // partial-tile epilogue (not hit at the bench shape)
  if (rem > 0 && blockIdx.x == (ntf % G)) {
    __syncthreads();
    const size_t base = (size_t)ntf * RPB * HOURS;
    for (int d = tid; d < rem * HOURS; d += 256) {
      float tv = ytrue[base + d];
      float pv = ypred[base + d];
      int pa = d + d / HOURS;
      ltp[0][pa] = __floats2half2_rn(tv, pv);
      float dd = (pv - tv) * (pv - tv);
      int h = d % HOURS;
      s_sq += dd;
      s_day += ((h >= 6) & (h <= 20)) ? dd : 0.f;
    }
    __syncthreads();
    if (tid < rem) compute_row(&ltp[0][tid * PSTR], s_pv, s_pt, s_shape, s_valid);
  }

  // block reduction: wave shuffle -> LDS across 4 waves -> per-block write
  float v[6] = {s_sq, s_day, s_pv, s_pt, s_shape, s_valid};
#pragma unroll
  for (int j = 0; j < 6; ++j) {
#pragma unroll
    for (int off = 32; off >= 1; off >>= 1) v[j] += __shfl_down(v[j], off, 64);
  }
  __shared__ float red[6][4];
  int lane = threadIdx.x & 63, wave = threadIdx.x >> 6;
  __syncthreads();
  if (lane == 0) {
#pragma unroll
    for (int j = 0; j < 6; ++j) red[j][wave] = v[j];
  }
  __syncthreads();
  if (threadIdx.x < 6) {
    int j = threadIdx.x;
    partials[(size_t)j * nblocks + blockIdx.x] =
        red[j][0] + red[j][1] + red[j][2] + red[j][3];
  }
}

// Single-block final reduction in fp64; writes the scalar loss.
__global__ __launch_bounds__(256) void peakloss_reduce(
    const float* __restrict__ partials, float* __restrict__ out,
    int nblocks, double inv_BS, double inv_BD) {
  double s[6] = {0, 0, 0, 0, 0, 0};
  for (int i = threadIdx.x; i < nblocks; i += 256) {
#pragma unroll
    for (int j = 0; j < 6; ++j) s[j] += (double)partials[(size_t)j * nblocks + i];
  }
#pragma unroll
  for (int j = 0; j < 6; ++j) {
#pragma unroll
    for (int off = 32; off >= 1; off >>= 1) s[j] += __shfl_down(s[j], off, 64);
  }
  __shared__ double red[6][4];
  int lane = threadIdx.x & 63, wave = threadIdx.x >> 6;
  if (lane == 0) {
#pragma unroll
    for (int j = 0; j < 6; ++j) red[j][wave] = s[j];
  }
  __syncthreads();
  if (threadIdx.x == 0) {
    double a[6];
#pragma unroll
    for (int j = 0; j < 6; ++j)
      a[j] = red[j][0] + red[j][1] + red[j][2] + red[j][3];
    double L_overall = a[0] * inv_BS;
    double L_day     = a[1] * inv_BS;          // weighted_mse - L_overall
    double L_pv      = a[2] * inv_BD;
    double L_pt      = a[3] * inv_BD;
    double L_shape   = a[4] / (a[5] + 1e-6);
    out[0] = (float)(L_overall + 2.0 * L_pv + L_pt + 0.5 * L_shape + 0.5 * L_day);
  }
}

extern "C" void kernel_launch(void* const* d_in, const int* in_sizes, int n_in,
                              void* d_out, int out_size, void* d_ws, size_t ws_size,
                              hipStream_t stream) {
  const float* ypred = (const float*)d_in[0];
  const float* ytrue = (const float*)d_in[1];
  float* out = (float*)d_out;
  float* partials = (float*)d_ws;

  long long N = in_sizes[0];          // B * S
  int nrows = (int)(N / HOURS);       // B * D
  int ntf = nrows / RPB;
  int grid = ntf > 0 ? (ntf < GRID_MAIN ? ntf : GRID_MAIN) : 1;

  peakloss_main<<<grid, 256, 0, stream>>>(ypred, ytrue, partials, nrows, grid);

  double inv_BS = 1.0 / (double)N;
  double inv_BD = 1.0 / (double)nrows;
  peakloss_reduce<<<1, 256, 0, stream>>>(partials, out, grid, inv_BS, inv_BD);
}